// Round 4
// baseline (81.798 us; speedup 1.0000x reference)
//
#include <hip/hip_runtime.h>

#define MARGIN 0.5f
#define NON_MATCH_W 1.0f

// ws layout: [u32 counter][pad][float msum][float nsum]  (16 B, memset to 0 each call)

__device__ __forceinline__ float4 ld_row_chunk(const float* __restrict__ base,
                                               int b, int row, int k, int N) {
    return reinterpret_cast<const float4*>(base + ((size_t)b * N + row) * 16)[k];
}

// 2 items per thread: item1 = gid (match or nonmatch), item2 = gid + half
// (always nonmatch). Region boundaries (80000, 440000) are multiples of 64
// -> wave-uniform predicates. All index loads issue up front (branchless
// pointer select), then all 4 row gathers.
__global__ __launch_bounds__(256) void cl_main(
    const float* __restrict__ outA, const float* __restrict__ outB,
    const int* __restrict__ matchA, const int* __restrict__ matchB,
    const int* __restrict__ nonMatchA, const int* __restrict__ nonMatchB,
    unsigned int* __restrict__ ws_counter, float* __restrict__ ws_sums,
    float* __restrict__ out,
    int N, int M, int Mn, int B, int nblocks, float invM, float invMn)
{
    const int totalMatchP = B * M;                 // 20000 pairs
    const int halfP = (B * M + B * Mn) >> 1;       // 110000 pairs as item1
    const int half = halfP * 4;                    // 440000 threads
    const int gid = blockIdx.x * blockDim.x + threadIdx.x;

    float msum = 0.0f;
    float nsum = 0.0f;

    if (gid < half) {
        const int k = gid & 3;
        const int p1 = gid >> 2;                        // [0, 110000)
        const int pair2 = p1 + (halfP - totalMatchP);   // flat nonmatch [90000, 200000)

        const bool isM = p1 < totalMatchP;
        const int flat1 = isM ? p1 : p1 - totalMatchP;
        const int* __restrict__ arrA1 = isM ? matchA : nonMatchA;
        const int* __restrict__ arrB1 = isM ? matchB : nonMatchB;

        // all 4 index loads issue here, unconditionally
        const int ia1 = arrA1[flat1];
        const int ib1 = arrB1[flat1];
        const int ia2 = nonMatchA[pair2];
        const int ib2 = nonMatchB[pair2];

        const int b1 = isM ? (p1 / M) : (flat1 / Mn);
        const int b2 = pair2 / Mn;

        // all 4 row gathers issue together
        const float4 a1 = ld_row_chunk(outA, b1, ia1, k, N);
        const float4 c1 = ld_row_chunk(outB, b1, ib1, k, N);
        const float4 a2 = ld_row_chunk(outA, b2, ia2, k, N);
        const float4 c2 = ld_row_chunk(outB, b2, ib2, k, N);

        // item1: per-component squares shared between sqdiff and hinge
        const float d1x = a1.x - c1.x, d1y = a1.y - c1.y,
                    d1z = a1.z - c1.z, d1w = a1.w - c1.w;
        const float q1x = d1x * d1x, q1y = d1y * d1y,
                    q1z = d1z * d1z, q1w = d1w * d1w;
        const float s1 = q1x + q1y + q1z + q1w;
        const float h1 = fmaxf(0.0f, MARGIN - q1x) + fmaxf(0.0f, MARGIN - q1y)
                       + fmaxf(0.0f, MARGIN - q1z) + fmaxf(0.0f, MARGIN - q1w);

        // item2: always hinge
        const float d2x = a2.x - c2.x, d2y = a2.y - c2.y,
                    d2z = a2.z - c2.z, d2w = a2.w - c2.w;
        const float q2x = d2x * d2x, q2y = d2y * d2y,
                    q2z = d2z * d2z, q2w = d2w * d2w;
        const float h2 = fmaxf(0.0f, MARGIN - q2x) + fmaxf(0.0f, MARGIN - q2y)
                       + fmaxf(0.0f, MARGIN - q2z) + fmaxf(0.0f, MARGIN - q2w);

        msum = isM ? s1 : 0.0f;
        nsum = (isM ? 0.0f : h1) + h2;
    }

    // wave-64 reduction
#pragma unroll
    for (int off = 32; off > 0; off >>= 1) {
        msum += __shfl_down(msum, off, 64);
        nsum += __shfl_down(nsum, off, 64);
    }

    __shared__ float sm[4];
    __shared__ float sn[4];
    const int wave = threadIdx.x >> 6;
    if ((threadIdx.x & 63) == 0) {
        sm[wave] = msum;
        sn[wave] = nsum;
    }
    __syncthreads();

    if (threadIdx.x == 0) {
        const float bm = sm[0] + sm[1] + sm[2] + sm[3];
        const float bn = sn[0] + sn[1] + sn[2] + sn[3];
        atomicAdd(&ws_sums[0], bm);
        atomicAdd(&ws_sums[1], bn);
        __threadfence();                       // order sum-atomics before counter
        const unsigned int old = atomicAdd(ws_counter, 1u);
        if (old == (unsigned int)(nblocks - 1)) {
            // last block: totals are complete at the coherent (atomic) point.
            // Read them back via atomic RMW to bypass any stale local L2 line.
            const float tm = atomicAdd(&ws_sums[0], 0.0f);
            const float tn = atomicAdd(&ws_sums[1], 0.0f);
            const float m = tm * invM;
            const float n = tn * NON_MATCH_W * invMn;
            out[0] = m + n;
            out[1] = m;
            out[2] = n;
        }
    }
}

extern "C" void kernel_launch(void* const* d_in, const int* in_sizes, int n_in,
                              void* d_out, int out_size, void* d_ws, size_t ws_size,
                              hipStream_t stream) {
    const float* outA = (const float*)d_in[0];
    const float* outB = (const float*)d_in[1];
    const int* matchA = (const int*)d_in[2];
    const int* matchB = (const int*)d_in[3];
    const int* nonMatchA = (const int*)d_in[4];
    const int* nonMatchB = (const int*)d_in[5];
    float* out = (float*)d_out;

    unsigned int* ws_counter = (unsigned int*)d_ws;
    float* ws_sums = (float*)((char*)d_ws + 8);

    const int B = 4;
    const int D = 16;
    const int N = in_sizes[0] / (B * D);   // 307200
    const int M = in_sizes[2] / B;         // 5000
    const int Mn = in_sizes[4] / B;        // 50000

    const int half = (B * M + B * Mn) * 2; // 440000 threads, 2 items each
    const int block = 256;
    const int grid = (half + block - 1) / block;   // 1719

    hipMemsetAsync(d_ws, 0, 16, stream);
    cl_main<<<grid, block, 0, stream>>>(outA, outB, matchA, matchB,
                                        nonMatchA, nonMatchB,
                                        ws_counter, ws_sums, out,
                                        N, M, Mn, B, grid,
                                        1.0f / (float)M, 1.0f / (float)Mn);
}

// Round 5
// 17.677 us; speedup vs baseline: 4.6275x; 4.6275x over previous
//
#include <hip/hip_runtime.h>

#define MARGIN 0.5f
#define NON_MATCH_W 1.0f

__device__ __forceinline__ float4 ld_row_chunk(const float* __restrict__ base,
                                               int b, int row, int k, int N) {
    return reinterpret_cast<const float4*>(base + ((size_t)b * N + row) * 16)[k];
}

__device__ __forceinline__ float sqsum4(float4 a, float4 b, float* q) {
    q[0] = (a.x - b.x) * (a.x - b.x);
    q[1] = (a.y - b.y) * (a.y - b.y);
    q[2] = (a.z - b.z) * (a.z - b.z);
    q[3] = (a.w - b.w) * (a.w - b.w);
    return q[0] + q[1] + q[2] + q[3];
}

__device__ __forceinline__ float hinge4(const float* q) {
    return fmaxf(0.0f, MARGIN - q[0]) + fmaxf(0.0f, MARGIN - q[1])
         + fmaxf(0.0f, MARGIN - q[2]) + fmaxf(0.0f, MARGIN - q[3]);
}

// 4 items per thread. Total items = 4 pair-chunks * 220000 pairs = 880000.
// Thread gid handles items {gid, gid+Q, gid+2Q, gid+3Q}, Q = 220000.
// Q % 4 == 0 so the chunk index k = gid & 3 is shared by all 4 items.
// Only item 0 can be a match pair (pairs < 20000); the boundary (gid=80000)
// is a multiple of 64 -> wave-uniform branch. Items 1-3 are always nonmatch.
__global__ __launch_bounds__(256) void cl_main(
    const float* __restrict__ outA, const float* __restrict__ outB,
    const int* __restrict__ matchA, const int* __restrict__ matchB,
    const int* __restrict__ nonMatchA, const int* __restrict__ nonMatchB,
    float* __restrict__ partials, int N, int M, int Mn, int B)
{
    const int totalP = B * M + B * Mn;       // 220000 pairs
    const int matchP = B * M;                // 20000 pairs
    const int Q = totalP;                    // items per quarter (880000/4)
    const int gid = blockIdx.x * blockDim.x + threadIdx.x;

    float msum = 0.0f;
    float nsum = 0.0f;

    if (gid < Q) {
        const int k = gid & 3;
        const int p = gid >> 2;              // [0, 55000)
        const int quarterP = totalP >> 2;    // 55000 pairs per quarter

        // ---- item 0: match or nonmatch (wave-uniform select)
        const bool isM = p < matchP;
        const int flat0 = isM ? p : p - matchP;
        const int* __restrict__ a0arr = isM ? matchA : nonMatchA;
        const int* __restrict__ b0arr = isM ? matchB : nonMatchB;

        // ---- items 1..3: always nonmatch
        const int flat1 = p + (quarterP - matchP);          // p + 35000
        const int flat2 = p + (2 * quarterP - matchP);      // p + 90000
        const int flat3 = p + (3 * quarterP - matchP);      // p + 145000

        // phase 1: all 8 index loads (coalesced)
        const int ia0 = a0arr[flat0];
        const int ib0 = b0arr[flat0];
        const int ia1 = nonMatchA[flat1];
        const int ib1 = nonMatchB[flat1];
        const int ia2 = nonMatchA[flat2];
        const int ib2 = nonMatchB[flat2];
        const int ia3 = nonMatchA[flat3];
        const int ib3 = nonMatchB[flat3];

        const int b0 = isM ? (p / M) : (flat0 / Mn);
        const int b1 = flat1 / Mn;
        const int b2 = flat2 / Mn;
        const int b3 = flat3 / Mn;

        // phase 2: all 8 row gathers in flight together
        const float4 A0 = ld_row_chunk(outA, b0, ia0, k, N);
        const float4 C0 = ld_row_chunk(outB, b0, ib0, k, N);
        const float4 A1 = ld_row_chunk(outA, b1, ia1, k, N);
        const float4 C1 = ld_row_chunk(outB, b1, ib1, k, N);
        const float4 A2 = ld_row_chunk(outA, b2, ia2, k, N);
        const float4 C2 = ld_row_chunk(outB, b2, ib2, k, N);
        const float4 A3 = ld_row_chunk(outA, b3, ia3, k, N);
        const float4 C3 = ld_row_chunk(outB, b3, ib3, k, N);

        // phase 3: math
        float q[4];
        const float s0 = sqsum4(A0, C0, q);
        const float h0 = hinge4(q);
        msum = isM ? s0 : 0.0f;
        nsum = isM ? 0.0f : h0;
        sqsum4(A1, C1, q); nsum += hinge4(q);
        sqsum4(A2, C2, q); nsum += hinge4(q);
        sqsum4(A3, C3, q); nsum += hinge4(q);
    }

    // wave-64 reduction
#pragma unroll
    for (int off = 32; off > 0; off >>= 1) {
        msum += __shfl_down(msum, off, 64);
        nsum += __shfl_down(nsum, off, 64);
    }

    __shared__ float sm[4];
    __shared__ float sn[4];
    const int wave = threadIdx.x >> 6;
    if ((threadIdx.x & 63) == 0) {
        sm[wave] = msum;
        sn[wave] = nsum;
    }
    __syncthreads();
    if (threadIdx.x == 0) {
        partials[2 * blockIdx.x]     = sm[0] + sm[1] + sm[2] + sm[3];
        partials[2 * blockIdx.x + 1] = sn[0] + sn[1] + sn[2] + sn[3];
    }
}

// Single-block deterministic reduction of per-block partials -> 3 outputs.
__global__ __launch_bounds__(256) void cl_finalize(
    const float* __restrict__ partials, float* __restrict__ out,
    int nblocks, float invM, float invMn)
{
    float msum = 0.0f;
    float nsum = 0.0f;
    const float2* p2 = reinterpret_cast<const float2*>(partials);
    for (int i = threadIdx.x; i < nblocks; i += 256) {
        const float2 v = p2[i];
        msum += v.x;
        nsum += v.y;
    }
#pragma unroll
    for (int off = 32; off > 0; off >>= 1) {
        msum += __shfl_down(msum, off, 64);
        nsum += __shfl_down(nsum, off, 64);
    }
    __shared__ float sm[4];
    __shared__ float sn[4];
    const int wave = threadIdx.x >> 6;
    if ((threadIdx.x & 63) == 0) {
        sm[wave] = msum;
        sn[wave] = nsum;
    }
    __syncthreads();
    if (threadIdx.x == 0) {
        const float m = (sm[0] + sm[1] + sm[2] + sm[3]) * invM;
        const float n = (sn[0] + sn[1] + sn[2] + sn[3]) * NON_MATCH_W * invMn;
        out[0] = m + n;
        out[1] = m;
        out[2] = n;
    }
}

extern "C" void kernel_launch(void* const* d_in, const int* in_sizes, int n_in,
                              void* d_out, int out_size, void* d_ws, size_t ws_size,
                              hipStream_t stream) {
    const float* outA = (const float*)d_in[0];
    const float* outB = (const float*)d_in[1];
    const int* matchA = (const int*)d_in[2];
    const int* matchB = (const int*)d_in[3];
    const int* nonMatchA = (const int*)d_in[4];
    const int* nonMatchB = (const int*)d_in[5];
    float* out = (float*)d_out;
    float* partials = (float*)d_ws;

    const int B = 4;
    const int D = 16;
    const int N = in_sizes[0] / (B * D);   // 307200
    const int M = in_sizes[2] / B;         // 5000
    const int Mn = in_sizes[4] / B;        // 50000

    const int Q = B * M + B * Mn;          // 220000 threads, 4 items each
    const int block = 256;
    const int grid = (Q + block - 1) / block;   // 860

    cl_main<<<grid, block, 0, stream>>>(outA, outB, matchA, matchB,
                                        nonMatchA, nonMatchB, partials, N, M, Mn, B);
    cl_finalize<<<1, block, 0, stream>>>(partials, out, grid,
                                         1.0f / (float)M, 1.0f / (float)Mn);
}

// Round 6
// 17.314 us; speedup vs baseline: 4.7244x; 1.0209x over previous
//
#include <hip/hip_runtime.h>

#define MARGIN 0.5f
#define NON_MATCH_W 1.0f

__device__ __forceinline__ float4 ld_row_chunk(const float* __restrict__ base,
                                               int b, int row, int k, int N) {
    return reinterpret_cast<const float4*>(base + ((size_t)b * N + row) * 16)[k];
}

// returns sum of squared diffs; h gets the hinge sum for the same chunk
__device__ __forceinline__ float sq_and_hinge(float4 a, float4 c, float& h) {
    const float dx = a.x - c.x, dy = a.y - c.y, dz = a.z - c.z, dw = a.w - c.w;
    const float qx = dx * dx, qy = dy * dy, qz = dz * dz, qw = dw * dw;
    h = fmaxf(0.0f, MARGIN - qx) + fmaxf(0.0f, MARGIN - qy)
      + fmaxf(0.0f, MARGIN - qz) + fmaxf(0.0f, MARGIN - qw);
    return qx + qy + qz + qw;
}

// 8 items per thread. Total items = 4 chunks * 220000 pairs = 880000.
// Thread gid handles items {gid + j*110000, j=0..7}; 110000 % 4 == 0 so the
// chunk index k = gid & 3 is shared by all 8 items. Pair of item j is
// p + j*27500 with p = gid>>2 in [0,27500). Only j=0 can be a match pair
// (matchP = 20000 < 27500); boundary gid = 80000 is a multiple of 64 ->
// wave-uniform branch. Items 1..7 are always nonmatch.
__global__ __launch_bounds__(256) void cl_main(
    const float* __restrict__ outA, const float* __restrict__ outB,
    const int* __restrict__ matchA, const int* __restrict__ matchB,
    const int* __restrict__ nonMatchA, const int* __restrict__ nonMatchB,
    float* __restrict__ partials, int N, int M, int Mn, int B)
{
    const int matchP = B * M;                  // 20000
    const int totalP = B * M + B * Mn;         // 220000
    const int PQ = totalP >> 3;                // 27500 pairs per eighth
    const int Q = totalP >> 1;                 // 110000 threads (= totalP*4/8)
    const int gid = blockIdx.x * blockDim.x + threadIdx.x;

    float msum = 0.0f;
    float nsum = 0.0f;

    if (gid < Q) {
        const int k = gid & 3;
        const int p = gid >> 2;                // [0, 27500)

        const bool isM = p < matchP;
        const int flat0 = isM ? p : p - matchP;
        const int* __restrict__ a0arr = isM ? matchA : nonMatchA;
        const int* __restrict__ b0arr = isM ? matchB : nonMatchB;

        // phase 1: all 16 index loads (wave-coalesced; 4 lanes share each int)
        int ia[8], ib[8];
        ia[0] = a0arr[flat0];
        ib[0] = b0arr[flat0];
#pragma unroll
        for (int j = 1; j < 8; ++j) {
            const int fj = p + j * PQ - matchP;    // nonmatch flat index
            ia[j] = nonMatchA[fj];
            ib[j] = nonMatchB[fj];
        }

        int bb[8];
        bb[0] = isM ? (p / M) : (flat0 / Mn);
#pragma unroll
        for (int j = 1; j < 8; ++j) {
            const int fj = p + j * PQ - matchP;
            bb[j] = fj / Mn;
        }

        // phase 2: all 16 row gathers in flight together
        float4 A[8], C[8];
#pragma unroll
        for (int j = 0; j < 8; ++j) {
            A[j] = ld_row_chunk(outA, bb[j], ia[j], k, N);
            C[j] = ld_row_chunk(outB, bb[j], ib[j], k, N);
        }

        // phase 3: math
        float h;
        const float s0 = sq_and_hinge(A[0], C[0], h);
        msum = isM ? s0 : 0.0f;
        nsum = isM ? 0.0f : h;
#pragma unroll
        for (int j = 1; j < 8; ++j) {
            sq_and_hinge(A[j], C[j], h);
            nsum += h;
        }
    }

    // wave-64 reduction
#pragma unroll
    for (int off = 32; off > 0; off >>= 1) {
        msum += __shfl_down(msum, off, 64);
        nsum += __shfl_down(nsum, off, 64);
    }

    __shared__ float sm[4];
    __shared__ float sn[4];
    const int wave = threadIdx.x >> 6;
    if ((threadIdx.x & 63) == 0) {
        sm[wave] = msum;
        sn[wave] = nsum;
    }
    __syncthreads();
    if (threadIdx.x == 0) {
        partials[2 * blockIdx.x]     = sm[0] + sm[1] + sm[2] + sm[3];
        partials[2 * blockIdx.x + 1] = sn[0] + sn[1] + sn[2] + sn[3];
    }
}

// Single-block deterministic reduction of per-block partials -> 3 outputs.
__global__ __launch_bounds__(256) void cl_finalize(
    const float* __restrict__ partials, float* __restrict__ out,
    int nblocks, float invM, float invMn)
{
    float msum = 0.0f;
    float nsum = 0.0f;
    const float2* p2 = reinterpret_cast<const float2*>(partials);
    for (int i = threadIdx.x; i < nblocks; i += 256) {
        const float2 v = p2[i];
        msum += v.x;
        nsum += v.y;
    }
#pragma unroll
    for (int off = 32; off > 0; off >>= 1) {
        msum += __shfl_down(msum, off, 64);
        nsum += __shfl_down(nsum, off, 64);
    }
    __shared__ float sm[4];
    __shared__ float sn[4];
    const int wave = threadIdx.x >> 6;
    if ((threadIdx.x & 63) == 0) {
        sm[wave] = msum;
        sn[wave] = nsum;
    }
    __syncthreads();
    if (threadIdx.x == 0) {
        const float m = (sm[0] + sm[1] + sm[2] + sm[3]) * invM;
        const float n = (sn[0] + sn[1] + sn[2] + sn[3]) * NON_MATCH_W * invMn;
        out[0] = m + n;
        out[1] = m;
        out[2] = n;
    }
}

extern "C" void kernel_launch(void* const* d_in, const int* in_sizes, int n_in,
                              void* d_out, int out_size, void* d_ws, size_t ws_size,
                              hipStream_t stream) {
    const float* outA = (const float*)d_in[0];
    const float* outB = (const float*)d_in[1];
    const int* matchA = (const int*)d_in[2];
    const int* matchB = (const int*)d_in[3];
    const int* nonMatchA = (const int*)d_in[4];
    const int* nonMatchB = (const int*)d_in[5];
    float* out = (float*)d_out;
    float* partials = (float*)d_ws;

    const int B = 4;
    const int D = 16;
    const int N = in_sizes[0] / (B * D);   // 307200
    const int M = in_sizes[2] / B;         // 5000
    const int Mn = in_sizes[4] / B;        // 50000

    const int Q = (B * M + B * Mn) / 2;    // 110000 threads, 8 items each
    const int block = 256;
    const int grid = (Q + block - 1) / block;   // 430

    cl_main<<<grid, block, 0, stream>>>(outA, outB, matchA, matchB,
                                        nonMatchA, nonMatchB, partials, N, M, Mn, B);
    cl_finalize<<<1, block, 0, stream>>>(partials, out, grid,
                                         1.0f / (float)M, 1.0f / (float)Mn);
}